// Round 3
// baseline (104.785 us; speedup 1.0000x reference)
//
#include <hip/hip_runtime.h>

#define IN_F 8192
#define OUT_F 8192
#define BATCH 64
#define TQ 32                   // output columns per tile
#define NT (OUT_F / TQ)         // 256 tiles
#define CAP_MAX 2048            // max entries per tile list
#define CH 256                  // entries per staged chunk in compute kernel
#define CNT_STRIDE 16           // ints: pad tile counters to 64B lines

// ---- d_ws layout (bytes) ----
// [0, 2MB)            xT: 8192 x 64 floats (transposed x)
// [2MB, 2MB+16KB)     tileCnt: NT * CNT_STRIDE ints
// [2MB+16KB, ...)     ent: NT * cap float4 {mu, k, amp, idx_bits}
#define XT_BYTES ((size_t)IN_F * BATCH * 4)
#define CNT_OFF  XT_BYTES
#define CNT_BYTES ((size_t)NT * CNT_STRIDE * 4)
#define ENT_OFF  (CNT_OFF + CNT_BYTES)

// ---------------- Kernel 0: zero the tile counters ----------------
__global__ __launch_bounds__(256) void zero_cnt_kern(int* __restrict__ cnt) {
    const int tid = threadIdx.x;
#pragma unroll
    for (int u = tid; u < NT * CNT_STRIDE; u += 256) cnt[u] = 0;
}

// ---------------- Kernel 1: transpose x + build per-tile band lists ----------------
// blocks [0,128): transpose 64-col slabs of x into xT
// blocks [128,160): one thread per feature, append to each overlapped tile's list
__global__ __launch_bounds__(256) void prep_kern(
    const float* __restrict__ x, float* __restrict__ xT,
    const float* __restrict__ mu, const float* __restrict__ sigma,
    const float* __restrict__ amp,
    int* __restrict__ cnt, float4* __restrict__ ent, const int cap) {

    const int tid = threadIdx.x;
    if (blockIdx.x < 128) {
        __shared__ float tile[64][65];
        const int i0 = blockIdx.x * 64;
#pragma unroll
        for (int u = tid; u < 64 * 64; u += 256) {
            const int b = u >> 6;
            const int i = u & 63;                  // fastest -> coalesced reads
            tile[i][b] = x[b * IN_F + i0 + i];
        }
        __syncthreads();
#pragma unroll
        for (int u = tid; u < 64 * 64; u += 256) {
            const int i = u >> 6;
            const int b = u & 63;                  // fastest -> coalesced writes
            xT[(i0 + i) * 64 + b] = tile[i][b];
        }
    } else {
        const int i = (blockIdx.x - 128) * 256 + tid;   // feature index, coalesced
        const float m = mu[i];
        const float s = sigma[i];
        const float a = amp[i];
        const float R = 8.0f * fabsf(s) + 1.0f;         // dropped weight < exp(-32)
        const float k = -0.5f / (s * s);
        // tile t covers cols [t*TQ, t*TQ+TQ-1]; include if band overlaps (+1 margin safe side)
        int t_lo = (int)floorf((m - R - (float)(TQ - 1)) * (1.0f / TQ));
        int t_hi = (int)floorf((m + R) * (1.0f / TQ)) + 1;
        t_lo = max(t_lo, 0);
        t_hi = min(t_hi, NT - 1);
        const float4 e = make_float4(m, k, a, __int_as_float(i));
        for (int t = t_lo; t <= t_hi; ++t) {
            const int p = atomicAdd(&cnt[t * CNT_STRIDE], 1);
            if (p < cap) ent[(size_t)t * cap + p] = e;
        }
    }
}

// ---------------- Kernel 2: banded Gaussian FC from prebuilt lists ----------------
// grid = (NT = 256 tiles, 4 batch quarters) = 1024 blocks -> 4 blocks/CU.
// block 256: c = tid&31 (col in tile), g = tid>>5 (0..7), 2 rows per thread.
__global__ __launch_bounds__(256, 4) void gauss_fc_kern(
    const float* __restrict__ xT, const int* __restrict__ cnt,
    const float4* __restrict__ ent, const float* __restrict__ bias,
    float* __restrict__ out, const int cap) {

    __shared__ float4 es[CH];          // 4 KB
    __shared__ float xs[CH][16];       // 16 KB

    const int tid = threadIdx.x;
    const int c = tid & 31;
    const int g = tid >> 5;
    const int t = blockIdx.x;
    const int row0 = blockIdx.y * 16;
    const int tile0 = t * TQ;
    const float colf = (float)(tile0 + c);
    const int n = min(cnt[t * CNT_STRIDE], cap);
    const float4* lst = ent + (size_t)t * cap;

    float acc0 = 0.f, acc1 = 0.f;

    for (int cb = 0; cb < n; cb += CH) {
        const int cn = min(CH, n - cb);
        // stage entries (1 float4 per thread)
        if (tid < cn) es[tid] = lst[cb + tid];
        __syncthreads();
        // gather x columns: per entry, 16 consecutive floats of xT as 4x float4
        for (int u = tid; u < (cn << 2); u += 256) {
            const int ci = u >> 2;
            const int rq = (u & 3) << 2;
            const int i = __float_as_int(es[ci].w);
            const float4 v = *(const float4*)&xT[i * 64 + row0 + rq];
            *(float4*)&xs[ci][rq] = v;
        }
        __syncthreads();

        const int g2 = g << 1;
#pragma unroll 4
        for (int j = 0; j < cn; ++j) {
            const float4 e = es[j];
            const float d = colf - e.x;
            const float w = e.z * __expf(e.y * d * d);
            acc0 += w * xs[j][g2 + 0];
            acc1 += w * xs[j][g2 + 1];
        }
        __syncthreads();
    }

    const float bb = bias[tile0 + c];
    const int r0 = row0 + (g << 1);
    const float v0 = acc0 + bb;
    const float v1 = acc1 + bb;
    out[(size_t)r0 * OUT_F + tile0 + c]       = v0 > 0.f ? v0 : 0.f;
    out[(size_t)(r0 + 1) * OUT_F + tile0 + c] = v1 > 0.f ? v1 : 0.f;
}

extern "C" void kernel_launch(void* const* d_in, const int* in_sizes, int n_in,
                              void* d_out, int out_size, void* d_ws, size_t ws_size,
                              hipStream_t stream) {
    const float* x     = (const float*)d_in[0];   // [64, 8192]
    const float* mu    = (const float*)d_in[1];   // [8192]
    const float* sigma = (const float*)d_in[2];   // [8192]
    const float* amp   = (const float*)d_in[3];   // [8192]
    const float* bias  = (const float*)d_in[4];   // [8192]
    float* out = (float*)d_out;

    char* ws = (char*)d_ws;
    float*  xT      = (float*)ws;
    int*    tileCnt = (int*)(ws + CNT_OFF);
    float4* ent     = (float4*)(ws + ENT_OFF);

    // runtime-clamp list capacity to workspace size (no OOB regardless of ws_size)
    int cap = CAP_MAX;
    if (ws_size < ENT_OFF + (size_t)NT * CAP_MAX * sizeof(float4)) {
        const size_t avail = (ws_size > ENT_OFF) ? (ws_size - ENT_OFF) : 0;
        cap = (int)(avail / ((size_t)NT * sizeof(float4)));
        if (cap < 1) cap = 1;   // degenerate; ws observed at 268MB so never hit
    }

    zero_cnt_kern<<<1, 256, 0, stream>>>(tileCnt);
    prep_kern<<<160, 256, 0, stream>>>(x, xT, mu, sigma, amp, tileCnt, ent, cap);
    dim3 grid(NT, BATCH / 16);
    gauss_fc_kern<<<grid, 256, 0, stream>>>(xT, tileCnt, ent, bias, out, cap);
}

// Round 5
// 91.971 us; speedup vs baseline: 1.1393x; 1.1393x over previous
//
#include <hip/hip_runtime.h>

#define IN_F 8192
#define OUT_F 8192
#define BATCH 64
#define TQ 64                   // output columns per tile
#define NTILE (OUT_F / TQ)      // 128 tiles
#define ROWS 16                 // batch rows per block (grid.y = 4)
#define PASS 2048               // feature-scan pass size; list cap == PASS => no overflow
#define CH 64                   // entries per chunk

// ---------------- Kernel 1: transpose x [64, 8192] -> xT [8192, 64] ----------------
__global__ __launch_bounds__(256) void transpose_x_kern(const float* __restrict__ x,
                                                        float* __restrict__ xT) {
    __shared__ float tile[64][65];   // +1 pad: conflict-free
    const int i0 = blockIdx.x * 64;
    const int tid = threadIdx.x;
#pragma unroll
    for (int u = tid; u < 64 * 64; u += 256) {
        const int b = u >> 6;
        const int i = u & 63;          // fastest -> coalesced reads
        tile[i][b] = x[b * IN_F + i0 + i];
    }
    __syncthreads();
#pragma unroll
    for (int u = tid; u < 64 * 64; u += 256) {
        const int i = u >> 6;
        const int b = u & 63;          // fastest -> coalesced writes
        xT[(i0 + i) * 64 + b] = tile[i][b];
    }
}

// ---------------- Kernel 2: banded Gaussian FC ----------------
// grid = (NTILE=128, 4) = 512 blocks -> 2 blocks/CU, 8 waves/CU.
// block 256: c = tid&31 -> cols (tile0+c, tile0+c+32); g = tid>>5 -> rows (2g, 2g+1).
// Inner loop per entry: 2 LDS w-reads + 1 LDS float2 x-read + 4 FMA (w precomputed).
__global__ __launch_bounds__(256, 2) void gauss_fc_kern(
    const float* __restrict__ x, const float* __restrict__ xT,
    const float4* __restrict__ mu4, const float4* __restrict__ sg4,
    const float* __restrict__ amp, const float* __restrict__ bias,
    float* __restrict__ out, const int use_xt) {

    __shared__ float4 list[PASS];        // {mu, kl, amp, idx_bits}  32 KB
    __shared__ float wtile[CH][64];      // weights per (entry, col) 16 KB
    __shared__ float xtile[CH][ROWS];    // x columns per (entry, row) 4 KB
    __shared__ int   cnt;

    const int tid = threadIdx.x;
    const int c = tid & 31;
    const int g = tid >> 5;              // 0..7
    const int g2 = g << 1;
    const int tile0 = blockIdx.x * TQ;
    const int row0 = blockIdx.y * ROWS;
    const float lo = (float)tile0;
    const float hi = (float)(tile0 + TQ - 1);

    float acc00 = 0.f, acc01 = 0.f, acc10 = 0.f, acc11 = 0.f;

    for (int base = 0; base < IN_F; base += PASS) {
        if (tid == 0) cnt = 0;
        __syncthreads();

        // ---- float4 scan + LDS compaction ----
        const int q_end = (base + PASS) >> 2;
        for (int q = (base >> 2) + tid; q < q_end; q += 256) {
            const float4 m4 = mu4[q];
            const float4 s4 = sg4[q];
            const float ms[4] = {m4.x, m4.y, m4.z, m4.w};
            const float ss[4] = {s4.x, s4.y, s4.z, s4.w};
#pragma unroll
            for (int e = 0; e < 4; ++e) {
                const float m = ms[e];
                const float s = ss[e];
                const float R = 8.0f * fabsf(s) + 1.0f;   // dropped weight < exp(-32)
                if (m >= lo - R && m <= hi + R) {
                    const int i = (q << 2) + e;
                    const int p = atomicAdd(&cnt, 1);     // p < PASS guaranteed
                    // kl = -log2(e)/(2 s^2): w = a * exp2(kl * d^2)
                    list[p] = make_float4(m, -0.72134752f / (s * s), amp[i],
                                          __int_as_float(i));
                }
            }
        }
        __syncthreads();
        const int n = cnt;

        // ---- chunks: precompute weight tile + gather x tile, then pure-FMA loop ----
        for (int cb = 0; cb < n; cb += CH) {
            const int cn = min(CH, n - cb);

            // weight tile: cn*64 exps over 256 threads (exp2f -> single v_exp_f32)
            for (int u = tid; u < (cn << 6); u += 256) {
                const int j = u >> 6;
                const int cc = u & 63;               // fastest -> conflict-free writes
                const float4 e = list[cb + j];
                const float d = (float)(tile0 + cc) - e.x;
                wtile[j][cc] = e.z * exp2f(e.y * d * d);
            }
            // x tile: 1 float4 per thread (4 threads per entry, 16B each)
            {
                const int ci = tid >> 2;
                const int rq = (tid & 3) << 2;
                if (ci < cn) {
                    const int i = __float_as_int(list[cb + ci].w);
                    if (use_xt) {
                        *(float4*)&xtile[ci][rq] = *(const float4*)&xT[i * 64 + row0 + rq];
                    } else {
                        xtile[ci][rq + 0] = x[(size_t)(row0 + rq + 0) * IN_F + i];
                        xtile[ci][rq + 1] = x[(size_t)(row0 + rq + 1) * IN_F + i];
                        xtile[ci][rq + 2] = x[(size_t)(row0 + rq + 2) * IN_F + i];
                        xtile[ci][rq + 3] = x[(size_t)(row0 + rq + 3) * IN_F + i];
                    }
                }
            }
            __syncthreads();

#pragma unroll 8
            for (int j = 0; j < cn; ++j) {
                const float w0 = wtile[j][c];
                const float w1 = wtile[j][c + 32];
                const float2 xv = *(const float2*)&xtile[j][g2];
                acc00 += w0 * xv.x;
                acc01 += w0 * xv.y;
                acc10 += w1 * xv.x;
                acc11 += w1 * xv.y;
            }
            __syncthreads();
        }
    }

    // ---- epilogue: + bias, ReLU, coalesced stores ----
    const float b0 = bias[tile0 + c];
    const float b1 = bias[tile0 + c + 32];
    const int r0 = row0 + g2;
    float* o0 = out + (size_t)r0 * OUT_F + tile0 + c;
    float* o1 = o0 + OUT_F;
    o0[0]  = fmaxf(acc00 + b0, 0.f);
    o1[0]  = fmaxf(acc01 + b0, 0.f);
    o0[32] = fmaxf(acc10 + b1, 0.f);
    o1[32] = fmaxf(acc11 + b1, 0.f);
}

extern "C" void kernel_launch(void* const* d_in, const int* in_sizes, int n_in,
                              void* d_out, int out_size, void* d_ws, size_t ws_size,
                              hipStream_t stream) {
    const float* x     = (const float*)d_in[0];   // [64, 8192]
    const float* mu    = (const float*)d_in[1];   // [8192]
    const float* sigma = (const float*)d_in[2];   // [8192]
    const float* amp   = (const float*)d_in[3];   // [8192]
    const float* bias  = (const float*)d_in[4];   // [8192]
    float* out = (float*)d_out;

    const size_t xt_bytes = (size_t)IN_F * BATCH * sizeof(float);
    const int use_xt = (ws_size >= xt_bytes) ? 1 : 0;
    float* xT = (float*)d_ws;

    if (use_xt) {
        transpose_x_kern<<<IN_F / 64, 256, 0, stream>>>(x, xT);
    }
    dim3 grid(NTILE, BATCH / ROWS);
    gauss_fc_kern<<<grid, 256, 0, stream>>>(x, xT,
                                            (const float4*)mu, (const float4*)sigma,
                                            amp, bias, out, use_xt);
}

// Round 6
// 86.422 us; speedup vs baseline: 1.2125x; 1.0642x over previous
//
#include <hip/hip_runtime.h>

#define IN_F 8192
#define OUT_F 8192
#define BATCH 64
#define TQ 64                   // output columns per tile
#define NTILE (OUT_F / TQ)      // 128 tiles
#define ROWS 16                 // batch rows per block (grid.y = 4)
#define PASS 2048               // feature-scan pass size; list cap == PASS => no overflow
#define CH 64                   // entries per chunk

// ---------------- Kernel 1: transpose x [64, 8192] -> xT [8192, 64] ----------------
__global__ __launch_bounds__(256) void transpose_x_kern(const float* __restrict__ x,
                                                        float* __restrict__ xT) {
    __shared__ float tile[64][65];   // +1 pad: conflict-free
    const int i0 = blockIdx.x * 64;
    const int tid = threadIdx.x;
#pragma unroll
    for (int u = tid; u < 64 * 64; u += 256) {
        const int b = u >> 6;
        const int i = u & 63;          // fastest -> coalesced reads
        tile[i][b] = x[b * IN_F + i0 + i];
    }
    __syncthreads();
#pragma unroll
    for (int u = tid; u < 64 * 64; u += 256) {
        const int i = u >> 6;
        const int b = u & 63;          // fastest -> coalesced writes
        xT[(i0 + i) * 64 + b] = tile[i][b];
    }
}

// ---------------- Kernel 2: banded Gaussian FC ----------------
// grid = (NTILE=128, 4) = 512 blocks -> 2 blocks/CU, 8 waves/CU.
// block 256: c = tid&31 -> adjacent cols (2c, 2c+1); g = tid>>5 -> rows (2g, 2g+1).
// Inner loop per entry: 1 ds_read_b64 (w pair) + 1 ds_read_b64 (x pair) + 4 FMA.
__global__ __launch_bounds__(256, 2) void gauss_fc_kern(
    const float* __restrict__ x, const float* __restrict__ xT,
    const float4* __restrict__ mu4, const float4* __restrict__ sg4,
    const float* __restrict__ amp, const float* __restrict__ bias,
    float* __restrict__ out, const int use_xt) {

    __shared__ float4 list[PASS];        // {mu, kl, amp, idx_bits}  32 KB
    __shared__ float wtile[CH][64];      // weights per (entry, col) 16 KB
    __shared__ float xtile[CH][ROWS];    // x columns per (entry, row) 4 KB
    __shared__ int   cnt;

    const int tid = threadIdx.x;
    const int cc = (tid & 31) << 1;      // col-pair base: 0,2,...,62
    const int g = tid >> 5;              // 0..7
    const int g2 = g << 1;
    const int tile0 = blockIdx.x * TQ;
    const int row0 = blockIdx.y * ROWS;
    const float lo = (float)tile0;
    const float hi = (float)(tile0 + TQ - 1);

    float acc00 = 0.f, acc01 = 0.f, acc10 = 0.f, acc11 = 0.f;

    for (int base = 0; base < IN_F; base += PASS) {
        if (tid == 0) cnt = 0;
        __syncthreads();

        // ---- float4 scan + LDS compaction ----
        const int q_end = (base + PASS) >> 2;
        for (int q = (base >> 2) + tid; q < q_end; q += 256) {
            const float4 m4 = mu4[q];
            const float4 s4 = sg4[q];
            const float ms[4] = {m4.x, m4.y, m4.z, m4.w};
            const float ss[4] = {s4.x, s4.y, s4.z, s4.w};
#pragma unroll
            for (int e = 0; e < 4; ++e) {
                const float m = ms[e];
                const float s = ss[e];
                // R = 5σ+1: dropped-tail absmax ~3e-5 << 0.3525 threshold
                const float R = 5.0f * fabsf(s) + 1.0f;
                if (m >= lo - R && m <= hi + R) {
                    const int i = (q << 2) + e;
                    const int p = atomicAdd(&cnt, 1);     // p < PASS guaranteed
                    // kl = -log2(e)/(2 s^2): w = a * exp2(kl * d^2)
                    list[p] = make_float4(m, -0.72134752f / (s * s), amp[i],
                                          __int_as_float(i));
                }
            }
        }
        __syncthreads();
        const int n = cnt;

        // ---- chunks: precompute weight tile + gather x tile, then pure-FMA loop ----
        for (int cb = 0; cb < n; cb += CH) {
            const int cn = min(CH, n - cb);

            // weight tile: cn*64 exps over 256 threads (exp2f -> single v_exp_f32)
            for (int u = tid; u < (cn << 6); u += 256) {
                const int j = u >> 6;
                const int col = u & 63;              // fastest -> conflict-free writes
                const float4 e = list[cb + j];
                const float d = (float)(tile0 + col) - e.x;
                wtile[j][col] = e.z * exp2f(e.y * d * d);
            }
            // x tile: 1 float4 per thread (4 threads per entry, 16B each)
            {
                const int ci = tid >> 2;
                const int rq = (tid & 3) << 2;
                if (ci < cn) {
                    const int i = __float_as_int(list[cb + ci].w);
                    if (use_xt) {
                        *(float4*)&xtile[ci][rq] = *(const float4*)&xT[i * 64 + row0 + rq];
                    } else {
                        xtile[ci][rq + 0] = x[(size_t)(row0 + rq + 0) * IN_F + i];
                        xtile[ci][rq + 1] = x[(size_t)(row0 + rq + 1) * IN_F + i];
                        xtile[ci][rq + 2] = x[(size_t)(row0 + rq + 2) * IN_F + i];
                        xtile[ci][rq + 3] = x[(size_t)(row0 + rq + 3) * IN_F + i];
                    }
                }
            }
            __syncthreads();

#pragma unroll 8
            for (int j = 0; j < cn; ++j) {
                const float2 wv = *(const float2*)&wtile[j][cc];   // ds_read_b64
                const float2 xv = *(const float2*)&xtile[j][g2];   // ds_read_b64 (broadcast)
                acc00 += wv.x * xv.x;
                acc01 += wv.x * xv.y;
                acc10 += wv.y * xv.x;
                acc11 += wv.y * xv.y;
            }
            __syncthreads();
        }
    }

    // ---- epilogue: + bias, ReLU, contiguous float2 stores ----
    const float b0 = bias[tile0 + cc];
    const float b1 = bias[tile0 + cc + 1];
    const int r0 = row0 + g2;
    float2 v0 = make_float2(fmaxf(acc00 + b0, 0.f), fmaxf(acc10 + b1, 0.f));
    float2 v1 = make_float2(fmaxf(acc01 + b0, 0.f), fmaxf(acc11 + b1, 0.f));
    *(float2*)&out[(size_t)r0 * OUT_F + tile0 + cc]       = v0;
    *(float2*)&out[(size_t)(r0 + 1) * OUT_F + tile0 + cc] = v1;
}

extern "C" void kernel_launch(void* const* d_in, const int* in_sizes, int n_in,
                              void* d_out, int out_size, void* d_ws, size_t ws_size,
                              hipStream_t stream) {
    const float* x     = (const float*)d_in[0];   // [64, 8192]
    const float* mu    = (const float*)d_in[1];   // [8192]
    const float* sigma = (const float*)d_in[2];   // [8192]
    const float* amp   = (const float*)d_in[3];   // [8192]
    const float* bias  = (const float*)d_in[4];   // [8192]
    float* out = (float*)d_out;

    const size_t xt_bytes = (size_t)IN_F * BATCH * sizeof(float);
    const int use_xt = (ws_size >= xt_bytes) ? 1 : 0;
    float* xT = (float*)d_ws;

    if (use_xt) {
        transpose_x_kern<<<IN_F / 64, 256, 0, stream>>>(x, xT);
    }
    dim3 grid(NTILE, BATCH / ROWS);
    gauss_fc_kern<<<grid, 256, 0, stream>>>(x, xT,
                                            (const float4*)mu, (const float4*)sigma,
                                            amp, bias, out, use_xt);
}